// Round 1
// baseline (504.721 us; speedup 1.0000x reference)
//
#include <hip/hip_runtime.h>
#include <math.h>

#define BT 32768   // B*T
#define NC 448     // n_embd
#define NH 64      // head_size

// ---------------- projection: kqv[p][R][h] = x[R][:] . W_p[h][:] ----------------
// grid 512 blocks (64 rows each), 256 threads, thread tile 4 rows x 12 outs
__global__ __launch_bounds__(256) void proj_kernel(
    const float* __restrict__ x, const float* __restrict__ Wk,
    const float* __restrict__ Wq, const float* __restrict__ Wv,
    float* __restrict__ kqv)
{
  __shared__ float xs[32][64];    // [c][r] transposed
  __shared__ float ws[32][192];   // [c][o] transposed
  const int tid = threadIdx.x;
  const int ty = tid >> 4, tx = tid & 15;
  const int r0 = blockIdx.x * 64;
  const float* Wp0[3] = {Wk, Wq, Wv};

  float acc[4][12];
#pragma unroll
  for (int i = 0; i < 4; ++i)
#pragma unroll
    for (int j = 0; j < 12; ++j) acc[i][j] = 0.f;

#pragma unroll 1
  for (int kc = 0; kc < NC; kc += 32) {
    // stage x chunk (coalesced float4 read, transposed LDS write)
#pragma unroll
    for (int k = 0; k < 2; ++k) {
      int f = tid + 256 * k;
      int r = f >> 3, c4 = f & 7;
      float4 v = *(const float4*)&x[(size_t)(r0 + r) * NC + kc + c4 * 4];
      xs[c4*4+0][r] = v.x; xs[c4*4+1][r] = v.y;
      xs[c4*4+2][r] = v.z; xs[c4*4+3][r] = v.w;
    }
    // stage W chunk for all 3 projections
#pragma unroll
    for (int k = 0; k < 6; ++k) {
      int f = tid + 256 * k;
      int o = f >> 3, c4 = f & 7;
      const float* W = Wp0[o >> 6];
      float4 v = *(const float4*)&W[(size_t)(o & 63) * NC + kc + c4 * 4];
      ws[c4*4+0][o] = v.x; ws[c4*4+1][o] = v.y;
      ws[c4*4+2][o] = v.z; ws[c4*4+3][o] = v.w;
    }
    __syncthreads();
#pragma unroll 8
    for (int c = 0; c < 32; ++c) {
      float4 xv = *(const float4*)&xs[c][ty*4];
      float4 wa = *(const float4*)&ws[c][tx*12];
      float4 wb = *(const float4*)&ws[c][tx*12+4];
      float4 wc = *(const float4*)&ws[c][tx*12+8];
      float xr[4] = {xv.x, xv.y, xv.z, xv.w};
      float wr[12] = {wa.x,wa.y,wa.z,wa.w, wb.x,wb.y,wb.z,wb.w, wc.x,wc.y,wc.z,wc.w};
#pragma unroll
      for (int i = 0; i < 4; ++i)
#pragma unroll
        for (int j = 0; j < 12; ++j) acc[i][j] += xr[i] * wr[j];
    }
    __syncthreads();
  }

  const float qscale = 0.047245559f; // 1/sqrt(448) -- reference scales by sqrt(n_embd)
#pragma unroll
  for (int i = 0; i < 4; ++i) {
    int R = r0 + ty*4 + i;
#pragma unroll
    for (int j = 0; j < 12; ++j) {
      int o = tx*12 + j;
      int p = o >> 6, oo = o & 63;
      float v = acc[i][j];
      if (p == 1) v *= qscale;           // pre-scale q
      kqv[(size_t)p * BT * NH + (size_t)R * NH + oo] = v;
    }
  }
}

// ---------------- flash attention (causal), fp32 VALU ----------------
// grid (32 qtiles, 16 batches), 256 threads, thread tile 4 rows x 4 cols
__global__ __launch_bounds__(256) void attn_kernel(
    const float* __restrict__ kqv, float* __restrict__ out)
{
  __shared__ float qs[64][64];   // [h][i] transposed
  __shared__ float ks[64][64];   // [h][j] transposed
  __shared__ float vs[64][64];   // [j][h] natural
  __shared__ float ps[64][64];   // [i][j]
  const int qt = blockIdx.x, b = blockIdx.y;
  const float* kbuf = kqv;
  const float* qbuf = kqv + (size_t)BT * NH;
  const float* vbuf = kqv + 2 * (size_t)BT * NH;
  const int tid = threadIdx.x;
  const int ty = tid >> 4, tx = tid & 15;
  const int t0 = b * 2048 + qt * 64;

  // stage Q transposed (once)
#pragma unroll
  for (int k = 0; k < 4; ++k) {
    int f = tid + 256 * k;
    int i = f >> 4, h4 = f & 15;
    float4 v = *(const float4*)&qbuf[(size_t)(t0 + i) * NH + h4 * 4];
    qs[h4*4+0][i] = v.x; qs[h4*4+1][i] = v.y;
    qs[h4*4+2][i] = v.z; qs[h4*4+3][i] = v.w;
  }

  float m_i[4], l_i[4], oacc[4][4];
#pragma unroll
  for (int i = 0; i < 4; ++i) {
    m_i[i] = -INFINITY; l_i[i] = 0.f;
#pragma unroll
    for (int j = 0; j < 4; ++j) oacc[i][j] = 0.f;
  }

  for (int kt = 0; kt <= qt; ++kt) {
    const int tk0 = b * 2048 + kt * 64;
    // stage K (transposed) and V (natural)
#pragma unroll
    for (int k = 0; k < 4; ++k) {
      int f = tid + 256 * k;
      int j = f >> 4, h4 = f & 15;
      float4 v = *(const float4*)&kbuf[(size_t)(tk0 + j) * NH + h4 * 4];
      ks[h4*4+0][j] = v.x; ks[h4*4+1][j] = v.y;
      ks[h4*4+2][j] = v.z; ks[h4*4+3][j] = v.w;
      float4 vv = *(const float4*)&vbuf[(size_t)(tk0 + j) * NH + h4 * 4];
      *(float4*)&vs[j][h4*4] = vv;
    }
    __syncthreads();

    // S = Q.K^T (q pre-scaled)
    float s[4][4];
#pragma unroll
    for (int i = 0; i < 4; ++i)
#pragma unroll
      for (int j = 0; j < 4; ++j) s[i][j] = 0.f;
#pragma unroll 8
    for (int h = 0; h < 64; ++h) {
      float4 qv = *(const float4*)&qs[h][ty*4];
      float4 kv = *(const float4*)&ks[h][tx*4];
      float qr[4] = {qv.x,qv.y,qv.z,qv.w};
      float kr[4] = {kv.x,kv.y,kv.z,kv.w};
#pragma unroll
      for (int i = 0; i < 4; ++i)
#pragma unroll
        for (int j = 0; j < 4; ++j) s[i][j] += qr[i]*kr[j];
    }

    if (kt == qt) {   // causal mask only triggers on diagonal tile
#pragma unroll
      for (int i = 0; i < 4; ++i) {
        int qi = ty*4 + i;
#pragma unroll
        for (int j = 0; j < 4; ++j)
          if (tx*4 + j > qi) s[i][j] = -INFINITY;
      }
    }

    // online softmax (row state replicated across the 16 tx lanes)
    float p[4][4];
#pragma unroll
    for (int i = 0; i < 4; ++i) {
      float rm = fmaxf(fmaxf(s[i][0], s[i][1]), fmaxf(s[i][2], s[i][3]));
      rm = fmaxf(rm, __shfl_xor(rm, 1));
      rm = fmaxf(rm, __shfl_xor(rm, 2));
      rm = fmaxf(rm, __shfl_xor(rm, 4));
      rm = fmaxf(rm, __shfl_xor(rm, 8));
      float mn = fmaxf(m_i[i], rm);
      float alpha = __expf(m_i[i] - mn);   // m_i=-inf, mn finite -> alpha=0 ok
      float rs = 0.f;
#pragma unroll
      for (int j = 0; j < 4; ++j) { p[i][j] = __expf(s[i][j] - mn); rs += p[i][j]; }
      rs += __shfl_xor(rs, 1); rs += __shfl_xor(rs, 2);
      rs += __shfl_xor(rs, 4); rs += __shfl_xor(rs, 8);
      l_i[i] = l_i[i] * alpha + rs;
      m_i[i] = mn;
#pragma unroll
      for (int j = 0; j < 4; ++j) oacc[i][j] *= alpha;
    }

    // write P tile (b128, conflict-free)
#pragma unroll
    for (int i = 0; i < 4; ++i)
      *(float4*)&ps[ty*4+i][tx*4] = make_float4(p[i][0], p[i][1], p[i][2], p[i][3]);
    __syncthreads();

    // O += P.V
#pragma unroll 4
    for (int jg = 0; jg < 16; ++jg) {
      float4 pv[4], vv[4];
#pragma unroll
      for (int i = 0; i < 4; ++i) pv[i] = *(const float4*)&ps[ty*4+i][jg*4];
#pragma unroll
      for (int j = 0; j < 4; ++j) vv[j] = *(const float4*)&vs[jg*4+j][tx*4];
#pragma unroll
      for (int i = 0; i < 4; ++i) {
        float pr[4] = {pv[i].x, pv[i].y, pv[i].z, pv[i].w};
#pragma unroll
        for (int j = 0; j < 4; ++j) {
          oacc[i][0] += pr[j]*vv[j].x;
          oacc[i][1] += pr[j]*vv[j].y;
          oacc[i][2] += pr[j]*vv[j].z;
          oacc[i][3] += pr[j]*vv[j].w;
        }
      }
    }
    __syncthreads();  // protect ks/vs/ps before next tile
  }

  // epilogue: divide by l, coalesced float4 stores
#pragma unroll
  for (int i = 0; i < 4; ++i) {
    float inv = 1.f / l_i[i];
    float4 o4 = make_float4(oacc[i][0]*inv, oacc[i][1]*inv,
                            oacc[i][2]*inv, oacc[i][3]*inv);
    *(float4*)&out[(size_t)(t0 + ty*4 + i) * NH + tx*4] = o4;
  }
}

extern "C" void kernel_launch(void* const* d_in, const int* in_sizes, int n_in,
                              void* d_out, int out_size, void* d_ws, size_t ws_size,
                              hipStream_t stream) {
  const float* x  = (const float*)d_in[0];
  const float* Wk = (const float*)d_in[1];
  const float* Wq = (const float*)d_in[2];
  const float* Wv = (const float*)d_in[3];
  float* kqv = (float*)d_ws;             // 3 * 32768 * 64 floats = 25.2 MB
  float* out = (float*)d_out;

  proj_kernel<<<512, 256, 0, stream>>>(x, Wk, Wq, Wv, kqv);
  attn_kernel<<<dim3(32, 16), 256, 0, stream>>>(kqv, out);
}

// Round 2
// 202.103 us; speedup vs baseline: 2.4973x; 2.4973x over previous
//
#include <hip/hip_runtime.h>
#include <math.h>

#define BT 32768   // B*T
#define NC 448     // n_embd
#define NH 64      // head_size
#define TT 2048    // T

typedef __bf16 bf16x8 __attribute__((ext_vector_type(8)));
typedef float  f32x4  __attribute__((ext_vector_type(4)));

// fp32 -> bf16 (RNE)
__device__ __forceinline__ unsigned short f2bf(float f) {
  unsigned u = __builtin_bit_cast(unsigned, f);
  return (unsigned short)((u + 0x7FFFu + ((u >> 16) & 1u)) >> 16);
}

// ============ projection: kqv_bf16[p][R][h] = bf16( x[R][:] . W_p[h][:] ) ============
// grid 512 (64 rows each), 256 thr = 4 waves; wave tile 16 rows x 192 cols.
// LDS rows are 64 bf16 (128 B) with chunk-granular XOR swizzle:
//   element (row, c) lives at row*64 + ((c>>3)^(row&7))*8 + (c&7)
// -> MFMA b128 fragment reads are 2-way max (free, m136); staging writes hit BW floor.
__global__ __launch_bounds__(256) void proj_kernel(
    const float* __restrict__ x, const float* __restrict__ Wk,
    const float* __restrict__ Wq, const float* __restrict__ Wv,
    unsigned short* __restrict__ kqv)
{
  __shared__ unsigned short xs[64 * 64];    // [r][c] swizzled
  __shared__ unsigned short ws[192 * 64];   // [o][c] swizzled
  const int tid = threadIdx.x;
  const int w = tid >> 6, lane = tid & 63;
  const int q = lane >> 4, l15 = lane & 15;
  const int r0 = blockIdx.x * 64;

  f32x4 acc[12];
#pragma unroll
  for (int i = 0; i < 12; ++i) acc[i] = f32x4{0.f, 0.f, 0.f, 0.f};

  const int c4 = tid & 15, r_ = tid >> 4;
  const int c0 = c4 * 4;

  for (int kc = 0; kc < NC; kc += 64) {
    __syncthreads();   // protect previous chunk's fragment reads
    // stage x chunk: 64 rows x 64 c (fp32 -> bf16)
#pragma unroll
    for (int rb = 0; rb < 4; ++rb) {
      int r = r_ + 16 * rb;
      float4 v = *(const float4*)&x[(size_t)(r0 + r) * NC + kc + c0];
      ushort4 bb; bb.x = f2bf(v.x); bb.y = f2bf(v.y); bb.z = f2bf(v.z); bb.w = f2bf(v.w);
      *(ushort4*)&xs[r * 64 + (((c0 >> 3) ^ (r & 7)) << 3) + (c0 & 7)] = bb;
    }
    // stage W chunk: 192 rows x 64 c
#pragma unroll
    for (int it = 0; it < 12; ++it) {
      const float* W = (it < 4) ? Wk : ((it < 8) ? Wq : Wv);
      int o = r_ + 16 * it;
      int row = r_ + 16 * (it & 3);
      float4 v = *(const float4*)&W[(size_t)row * NC + kc + c0];
      ushort4 bb; bb.x = f2bf(v.x); bb.y = f2bf(v.y); bb.z = f2bf(v.z); bb.w = f2bf(v.w);
      *(ushort4*)&ws[o * 64 + (((c0 >> 3) ^ (o & 7)) << 3) + (c0 & 7)] = bb;
    }
    __syncthreads();

#pragma unroll
    for (int ks = 0; ks < 2; ++ks) {
      int arow = w * 16 + l15;
      bf16x8 a = *(const bf16x8*)&xs[arow * 64 + (((q + 4 * ks) ^ (arow & 7)) << 3)];
#pragma unroll
      for (int ct = 0; ct < 12; ++ct) {
        int brow = ct * 16 + l15;
        bf16x8 bf = *(const bf16x8*)&ws[brow * 64 + (((q + 4 * ks) ^ (brow & 7)) << 3)];
        acc[ct] = __builtin_amdgcn_mfma_f32_16x16x32_bf16(a, bf, acc[ct], 0, 0, 0);
      }
    }
  }

  // q pre-scaled by log2(e)/sqrt(448) so attention can use exp2 directly
  const float qs = 0.068161075f;
#pragma unroll
  for (int ct = 0; ct < 12; ++ct) {
    int o = ct * 16 + l15;
    int p = o >> 6, h = o & 63;
    float sc = (p == 1) ? qs : 1.f;
#pragma unroll
    for (int rr = 0; rr < 4; ++rr) {
      int R = r0 + w * 16 + q * 4 + rr;   // C/D layout: row = quad*4+reg, col = lane&15
      kqv[(size_t)p * BT * NH + (size_t)R * NH + h] = f2bf(acc[ct][rr] * sc);
    }
  }
}

// ============ flash attention (causal), bf16 MFMA ============
// grid (32,16), qt = 31 - blockIdx.x (long blocks first); 256 thr = 4 waves.
// Wave w owns 16 q-rows; K in LDS [j][h], V transposed [h][j], P round-trip [i][j],
// all 64-wide swizzled rows. P rows are wave-private -> no barrier for the round-trip.
__global__ __launch_bounds__(256) void attn_kernel(
    const unsigned short* __restrict__ kqv, float* __restrict__ out)
{
  __shared__ unsigned short ksm[64 * 64];
  __shared__ unsigned short vtm[64 * 64];
  __shared__ unsigned short psm[64 * 64];
  const int qt = 31 - (int)blockIdx.x, b = blockIdx.y;
  const unsigned short* kb = kqv;
  const unsigned short* qb = kqv + (size_t)BT * NH;
  const unsigned short* vb = kqv + 2 * (size_t)BT * NH;
  const int tid = threadIdx.x;
  const int w = tid >> 6, lane = tid & 63;
  const int q = lane >> 4, l15 = lane & 15;
  const int t0 = b * TT + qt * 64;

  // Q fragments (held in registers for the whole block)
  bf16x8 qf[2];
#pragma unroll
  for (int ks2 = 0; ks2 < 2; ++ks2)
    qf[ks2] = *(const bf16x8*)&qb[(size_t)(t0 + w * 16 + l15) * NH + q * 8 + 32 * ks2];

  f32x4 oacc[4];
  float m_i[4], l_i[4];
#pragma unroll
  for (int rr = 0; rr < 4; ++rr) { m_i[rr] = -INFINITY; l_i[rr] = 0.f; }
#pragma unroll
  for (int ht = 0; ht < 4; ++ht) oacc[ht] = f32x4{0.f, 0.f, 0.f, 0.f};

  for (int kt = 0; kt <= qt; ++kt) {
    const int tk0 = b * TT + kt * 64;
    __syncthreads();   // previous iteration's ksm/vtm reads complete
    // stage K: rows [j][h], swizzled; coalesced 16B copies
    {
      int hc = tid & 7, j0 = tid >> 3;
#pragma unroll
      for (int pass = 0; pass < 2; ++pass) {
        int j = j0 + 32 * pass;
        uint4 v = *(const uint4*)&kb[(size_t)(tk0 + j) * NH + hc * 8];
        *(uint4*)&ksm[j * 64 + ((hc ^ (j & 7)) << 3)] = v;
      }
      // stage V transposed: vtm[h][j]
      int jv = tid & 63, hc2 = tid >> 6;
#pragma unroll
      for (int q2 = 0; q2 < 2; ++q2) {
        int h0 = hc2 * 16 + q2 * 8;
        union { uint4 v; unsigned short e[8]; } uv;
        uv.v = *(const uint4*)&vb[(size_t)(tk0 + jv) * NH + h0];
#pragma unroll
        for (int u = 0; u < 8; ++u) {
          int h = h0 + u;
          vtm[h * 64 + (((jv >> 3) ^ (h & 7)) << 3) + (jv & 7)] = uv.e[u];
        }
      }
    }
    __syncthreads();

    // S = Q . K^T  (16 x 64 per wave)
    f32x4 sacc[4];
#pragma unroll
    for (int jt = 0; jt < 4; ++jt) sacc[jt] = f32x4{0.f, 0.f, 0.f, 0.f};
#pragma unroll
    for (int jt = 0; jt < 4; ++jt) {
      int krow = jt * 16 + l15;
#pragma unroll
      for (int ks2 = 0; ks2 < 2; ++ks2) {
        bf16x8 kf = *(const bf16x8*)&ksm[krow * 64 + (((q + 4 * ks2) ^ (l15 & 7)) << 3)];
        sacc[jt] = __builtin_amdgcn_mfma_f32_16x16x32_bf16(qf[ks2], kf, sacc[jt], 0, 0, 0);
      }
    }

    if (kt == qt) {   // causal mask: only the diagonal tile is partial
#pragma unroll
      for (int jt = 0; jt < 4; ++jt) {
        int kj = jt * 16 + l15;
#pragma unroll
        for (int rr = 0; rr < 4; ++rr)
          if (kj > w * 16 + q * 4 + rr) sacc[jt][rr] = -INFINITY;
      }
    }

    // online softmax in exp2 domain (q pre-scaled by log2e/sqrt(C))
    float p_[4][4];   // [jt][rr]
#pragma unroll
    for (int rr = 0; rr < 4; ++rr) {
      float mx = fmaxf(fmaxf(sacc[0][rr], sacc[1][rr]), fmaxf(sacc[2][rr], sacc[3][rr]));
      mx = fmaxf(mx, __shfl_xor(mx, 1));
      mx = fmaxf(mx, __shfl_xor(mx, 2));
      mx = fmaxf(mx, __shfl_xor(mx, 4));
      mx = fmaxf(mx, __shfl_xor(mx, 8));
      float mn = fmaxf(m_i[rr], mx);
      float alpha = exp2f(m_i[rr] - mn);   // first tile: exp2(-inf)=0
      m_i[rr] = mn;
      float rs = 0.f;
#pragma unroll
      for (int jt = 0; jt < 4; ++jt) {
        float pv = exp2f(sacc[jt][rr] - mn);
        p_[jt][rr] = pv; rs += pv;
      }
      rs += __shfl_xor(rs, 1); rs += __shfl_xor(rs, 2);
      rs += __shfl_xor(rs, 4); rs += __shfl_xor(rs, 8);
      l_i[rr] = l_i[rr] * alpha + rs;
      oacc[0][rr] *= alpha; oacc[1][rr] *= alpha;
      oacc[2][rr] *= alpha; oacc[3][rr] *= alpha;
    }

    // P -> LDS (bf16) ; rows are wave-private so no barrier needed
#pragma unroll
    for (int jt = 0; jt < 4; ++jt) {
      int col = jt * 16 + l15;
#pragma unroll
      for (int rr = 0; rr < 4; ++rr) {
        int row = w * 16 + q * 4 + rr;
        psm[row * 64 + (((col >> 3) ^ (row & 7)) << 3) + (col & 7)] = f2bf(p_[jt][rr]);
      }
    }

    // O += P . V
#pragma unroll
    for (int js = 0; js < 2; ++js) {
      int arow = w * 16 + l15;
      bf16x8 af = *(const bf16x8*)&psm[arow * 64 + (((q + 4 * js) ^ (l15 & 7)) << 3)];
#pragma unroll
      for (int ht = 0; ht < 4; ++ht) {
        int vrow = ht * 16 + l15;
        bf16x8 vf = *(const bf16x8*)&vtm[vrow * 64 + (((q + 4 * js) ^ (l15 & 7)) << 3)];
        oacc[ht] = __builtin_amdgcn_mfma_f32_16x16x32_bf16(af, vf, oacc[ht], 0, 0, 0);
      }
    }
  }

  // epilogue: O /= l
#pragma unroll
  for (int rr = 0; rr < 4; ++rr) {
    float inv = 1.f / l_i[rr];
    int R = t0 + w * 16 + q * 4 + rr;
#pragma unroll
    for (int ht = 0; ht < 4; ++ht)
      out[(size_t)R * NH + ht * 16 + l15] = oacc[ht][rr] * inv;
  }
}

extern "C" void kernel_launch(void* const* d_in, const int* in_sizes, int n_in,
                              void* d_out, int out_size, void* d_ws, size_t ws_size,
                              hipStream_t stream) {
  const float* x  = (const float*)d_in[0];
  const float* Wk = (const float*)d_in[1];
  const float* Wq = (const float*)d_in[2];
  const float* Wv = (const float*)d_in[3];
  unsigned short* kqv = (unsigned short*)d_ws;   // bf16 [3][32768][64] = 12.6 MB
  float* out = (float*)d_out;

  proj_kernel<<<512, 256, 0, stream>>>(x, Wk, Wq, Wv, kqv);
  attn_kernel<<<dim3(32, 16), 256, 0, stream>>>(kqv, out);
}

// Round 3
// 172.100 us; speedup vs baseline: 2.9327x; 1.1743x over previous
//
#include <hip/hip_runtime.h>
#include <math.h>

#define BT 32768   // B*T
#define NC 448     // n_embd
#define NH 64      // head_size
#define TT 2048    // T

typedef __bf16 bf16x8 __attribute__((ext_vector_type(8)));
typedef float  f32x4  __attribute__((ext_vector_type(4)));

// fp32 -> bf16 (RNE)
__device__ __forceinline__ unsigned short f2bf(float f) {
  unsigned u = __builtin_bit_cast(unsigned, f);
  return (unsigned short)((u + 0x7FFFu + ((u >> 16) & 1u)) >> 16);
}

// Swizzled 64x64 bf16 tile: element (row, c) at row*64 + (((c>>3) ^ (row&7))<<3) + (c&7)
// b128 fragment reads are <=2-way bank aliased (free, m136).

// ============ projection ============
// Outputs (all bf16, in d_ws):
//   kws: per (b,kt) 64x64 tile, K-rows swizzled image  (attn DMA-copies verbatim)
//   qws: natural [R][h], pre-scaled by log2e/sqrt(448)
//   vws: per (b,kt) 64x64 tile of V^T ([h][j]) swizzled image
// k is computed operand-swapped (A=W, B=x) so its fragment stores are ushort4.
__global__ __launch_bounds__(256) void proj_kernel(
    const float* __restrict__ x, const float* __restrict__ Wk,
    const float* __restrict__ Wq, const float* __restrict__ Wv,
    unsigned short* __restrict__ kws, unsigned short* __restrict__ qws,
    unsigned short* __restrict__ vws)
{
  __shared__ unsigned short xs[64 * 64];     // [r][c] swizzled
  __shared__ unsigned short wsm[192 * 64];   // [o][c] swizzled (Wk|Wq|Wv rows)
  const int tid = threadIdx.x;
  const int w = tid >> 6, lane = tid & 63;
  const int q = lane >> 4, l15 = lane & 15;
  const int r0 = blockIdx.x * 64;            // 64 rows = one (b,kt) tile

  f32x4 acc[12];   // 0-3: k^T tiles, 4-7: q, 8-11: v
#pragma unroll
  for (int i = 0; i < 12; ++i) acc[i] = f32x4{0.f, 0.f, 0.f, 0.f};

  const int c0 = (tid & 15) * 4, r_ = tid >> 4;

  for (int kc = 0; kc < NC; kc += 64) {
    __syncthreads();
#pragma unroll
    for (int rb = 0; rb < 4; ++rb) {
      int r = r_ + 16 * rb;
      float4 v = *(const float4*)&x[(size_t)(r0 + r) * NC + kc + c0];
      ushort4 bb; bb.x = f2bf(v.x); bb.y = f2bf(v.y); bb.z = f2bf(v.z); bb.w = f2bf(v.w);
      *(ushort4*)&xs[r * 64 + (((c0 >> 3) ^ (r & 7)) << 3) + (c0 & 7)] = bb;
    }
#pragma unroll
    for (int it = 0; it < 12; ++it) {
      const float* W = (it < 4) ? Wk : ((it < 8) ? Wq : Wv);
      int o = r_ + 16 * it;
      int row = r_ + 16 * (it & 3);
      float4 v = *(const float4*)&W[(size_t)row * NC + kc + c0];
      ushort4 bb; bb.x = f2bf(v.x); bb.y = f2bf(v.y); bb.z = f2bf(v.z); bb.w = f2bf(v.w);
      *(ushort4*)&wsm[o * 64 + (((c0 >> 3) ^ (o & 7)) << 3) + (c0 & 7)] = bb;
    }
    __syncthreads();

#pragma unroll
    for (int ks = 0; ks < 2; ++ks) {
      int arow = w * 16 + l15;
      bf16x8 xa = *(const bf16x8*)&xs[arow * 64 + (((q + 4 * ks) ^ (arow & 7)) << 3)];
#pragma unroll
      for (int t = 0; t < 12; ++t) {
        int brow = t * 16 + l15;
        bf16x8 bf = *(const bf16x8*)&wsm[brow * 64 + (((q + 4 * ks) ^ (brow & 7)) << 3)];
        if (t < 4)
          acc[t] = __builtin_amdgcn_mfma_f32_16x16x32_bf16(bf, xa, acc[t], 0, 0, 0);
        else
          acc[t] = __builtin_amdgcn_mfma_f32_16x16x32_bf16(xa, bf, acc[t], 0, 0, 0);
      }
    }
  }

  const size_t tile = (size_t)blockIdx.x * 4096;
  // ---- k: lane holds k^T[h = wt*16+q*4+rr][j = w*16+l15]; swizzled ushort4 stores
#pragma unroll
  for (int wt = 0; wt < 4; ++wt) {
    int j = w * 16 + l15;
    ushort4 bb; bb.x = f2bf(acc[wt][0]); bb.y = f2bf(acc[wt][1]);
    bb.z = f2bf(acc[wt][2]); bb.w = f2bf(acc[wt][3]);
    *(ushort4*)&kws[tile + j * 64 + (((2 * wt + (q >> 1)) ^ (j & 7)) << 3) + ((q & 1) << 2)] = bb;
  }
  // ---- q: natural [R][h], scaled by log2(e)/sqrt(448); scalar u16 stores
  const float qs = 0.068161075f;
#pragma unroll
  for (int ct = 4; ct < 8; ++ct) {
    int h = (ct - 4) * 16 + l15;
#pragma unroll
    for (int rr = 0; rr < 4; ++rr) {
      int R = r0 + w * 16 + q * 4 + rr;
      qws[(size_t)R * 64 + h] = f2bf(acc[ct][rr] * qs);
    }
  }
  // ---- v: lane holds v[j = w*16+q*4+rr][h = (ct-8)*16+l15] -> V^T tile, ushort4
#pragma unroll
  for (int ct = 8; ct < 12; ++ct) {
    int h = (ct - 8) * 16 + l15;
    ushort4 bb; bb.x = f2bf(acc[ct][0]); bb.y = f2bf(acc[ct][1]);
    bb.z = f2bf(acc[ct][2]); bb.w = f2bf(acc[ct][3]);
    *(ushort4*)&vws[tile + h * 64 + (((2 * w + (q >> 1)) ^ (h & 7)) << 3) + ((q & 1) << 2)] = bb;
  }
}

// ============ flash attention (causal), S^T formulation ============
// grid (32,16), qt = 31-bx; 256 thr = 4 waves; wave w owns 16 q-rows (i = l15).
// S^T = K.Q^T  -> softmax state per-lane (i = l15) -> P via wave-private LDS
// round-trip -> O = P.V with V^T tiles. K/V double-buffered, register prefetch,
// ONE barrier per iteration (dbuf makes the trailing barrier unnecessary).
__global__ __launch_bounds__(256) void attn_kernel(
    const unsigned short* __restrict__ kws, const unsigned short* __restrict__ qws,
    const unsigned short* __restrict__ vws, float* __restrict__ out)
{
  __shared__ unsigned short ksm[2][4096];
  __shared__ unsigned short vtm[2][4096];
  __shared__ unsigned short psm[4096];
  const int qt = 31 - (int)blockIdx.x, b = blockIdx.y;
  const int tid = threadIdx.x;
  const int w = tid >> 6, lane = tid & 63;
  const int q = lane >> 4, l15 = lane & 15;
  const int t0 = b * TT + qt * 64;
  const int l7 = l15 & 7;

  // Q fragments (B-operand: lane i = l15, contiguous c)
  bf16x8 qf[2];
#pragma unroll
  for (int ks = 0; ks < 2; ++ks)
    qf[ks] = *(const bf16x8*)&qws[(size_t)(t0 + w * 16 + l15) * 64 + 32 * ks + q * 8];

  f32x4 oacc[4];
#pragma unroll
  for (int ht = 0; ht < 4; ++ht) oacc[ht] = f32x4{0.f, 0.f, 0.f, 0.f};
  float m_i = -INFINITY, l_i = 0.f;   // per-lane: row i = l15

  // register prefetch of tile kt (pre-swizzled global image -> linear copy)
  uint4 kr0, kr1, vr0, vr1;
  {
    const unsigned short* kt_ = kws + (size_t)(b * 32 + 0) * 4096;
    const unsigned short* vt_ = vws + (size_t)(b * 32 + 0) * 4096;
    kr0 = *(const uint4*)&kt_[tid * 8];  kr1 = *(const uint4*)&kt_[2048 + tid * 8];
    vr0 = *(const uint4*)&vt_[tid * 8];  vr1 = *(const uint4*)&vt_[2048 + tid * 8];
  }

  for (int kt = 0; kt <= qt; ++kt) {
    const int cur = kt & 1;
    *(uint4*)&ksm[cur][tid * 8] = kr0;  *(uint4*)&ksm[cur][2048 + tid * 8] = kr1;
    *(uint4*)&vtm[cur][tid * 8] = vr0;  *(uint4*)&vtm[cur][2048 + tid * 8] = vr1;
    __syncthreads();
    if (kt < qt) {
      const unsigned short* kt_ = kws + (size_t)(b * 32 + kt + 1) * 4096;
      const unsigned short* vt_ = vws + (size_t)(b * 32 + kt + 1) * 4096;
      kr0 = *(const uint4*)&kt_[tid * 8];  kr1 = *(const uint4*)&kt_[2048 + tid * 8];
      vr0 = *(const uint4*)&vt_[tid * 8];  vr1 = *(const uint4*)&vt_[2048 + tid * 8];
    }

    // S^T = K . Q^T : D[m=j][n=i]; lane: j = jt*16+q*4+rr, i = l15
    f32x4 sacc[4];
#pragma unroll
    for (int jt = 0; jt < 4; ++jt) sacc[jt] = f32x4{0.f, 0.f, 0.f, 0.f};
#pragma unroll
    for (int jt = 0; jt < 4; ++jt) {
      int j = jt * 16 + l15;
#pragma unroll
      for (int ks = 0; ks < 2; ++ks) {
        bf16x8 kf = *(const bf16x8*)&ksm[cur][j * 64 + (((q + 4 * ks) ^ (j & 7)) << 3)];
        sacc[jt] = __builtin_amdgcn_mfma_f32_16x16x32_bf16(kf, qf[ks], sacc[jt], 0, 0, 0);
      }
    }

    if (kt == qt) {   // causal: mask j > i on the diagonal tile
      int iloc = w * 16 + l15;
#pragma unroll
      for (int jt = 0; jt < 4; ++jt)
#pragma unroll
        for (int rr = 0; rr < 4; ++rr)
          if (jt * 16 + q * 4 + rr > iloc) sacc[jt][rr] = -INFINITY;
    }

    // online softmax: all 16 values in this lane share row i = l15
    float mx = -INFINITY;
#pragma unroll
    for (int jt = 0; jt < 4; ++jt)
#pragma unroll
      for (int rr = 0; rr < 4; ++rr) mx = fmaxf(mx, sacc[jt][rr]);
    mx = fmaxf(mx, __shfl_xor(mx, 16));
    mx = fmaxf(mx, __shfl_xor(mx, 32));
    float mn = fmaxf(m_i, mx);
    float alpha = exp2f(m_i - mn);
    m_i = mn;
    float p[4][4], rs = 0.f;
#pragma unroll
    for (int jt = 0; jt < 4; ++jt)
#pragma unroll
      for (int rr = 0; rr < 4; ++rr) {
        float pv = exp2f(sacc[jt][rr] - mn);
        p[jt][rr] = pv; rs += pv;
      }
    rs += __shfl_xor(rs, 16);
    rs += __shfl_xor(rs, 32);
    l_i = l_i * alpha + rs;

    // alpha transpose: O rows are i = q*4+rr; alpha lives at lane l15 = i
    float a_t[4];
#pragma unroll
    for (int rr = 0; rr < 4; ++rr) a_t[rr] = __shfl(alpha, q * 4 + rr);
#pragma unroll
    for (int ht = 0; ht < 4; ++ht)
#pragma unroll
      for (int rr = 0; rr < 4; ++rr) oacc[ht][rr] *= a_t[rr];

    // P -> LDS (wave-private rows, no barrier): row = w*16+l15, cols j = jt*16+q*4+rr
    {
      int row = w * 16 + l15;
#pragma unroll
      for (int jt = 0; jt < 4; ++jt) {
        ushort4 bb; bb.x = f2bf(p[jt][0]); bb.y = f2bf(p[jt][1]);
        bb.z = f2bf(p[jt][2]); bb.w = f2bf(p[jt][3]);
        *(ushort4*)&psm[row * 64 + (((2 * jt + (q >> 1)) ^ l7) << 3) + ((q & 1) << 2)] = bb;
      }
    }

    // O += P . V : A = P rows (m=i=l15), B = V^T rows (n=h=l15 per ht)
#pragma unroll
    for (int ks2 = 0; ks2 < 2; ++ks2) {
      int prow = w * 16 + l15;
      bf16x8 pf = *(const bf16x8*)&psm[prow * 64 + (((q + 4 * ks2) ^ l7) << 3)];
#pragma unroll
      for (int ht = 0; ht < 4; ++ht) {
        int h = ht * 16 + l15;
        bf16x8 vf = *(const bf16x8*)&vtm[cur][h * 64 + (((q + 4 * ks2) ^ l7) << 3)];
        oacc[ht] = __builtin_amdgcn_mfma_f32_16x16x32_bf16(pf, vf, oacc[ht], 0, 0, 0);
      }
    }
  }

  // epilogue: O[m=i=q*4+rr][n=h]; l lives at lane l15 = i -> transpose via shuffle
  float l_t[4];
#pragma unroll
  for (int rr = 0; rr < 4; ++rr) l_t[rr] = __shfl(l_i, q * 4 + rr);
#pragma unroll
  for (int rr = 0; rr < 4; ++rr) {
    float inv = 1.f / l_t[rr];
    int R = t0 + w * 16 + q * 4 + rr;
#pragma unroll
    for (int ht = 0; ht < 4; ++ht)
      out[(size_t)R * 64 + ht * 16 + l15] = oacc[ht][rr] * inv;
  }
}

extern "C" void kernel_launch(void* const* d_in, const int* in_sizes, int n_in,
                              void* d_out, int out_size, void* d_ws, size_t ws_size,
                              hipStream_t stream) {
  const float* x  = (const float*)d_in[0];
  const float* Wk = (const float*)d_in[1];
  const float* Wq = (const float*)d_in[2];
  const float* Wv = (const float*)d_in[3];
  unsigned short* kws = (unsigned short*)d_ws;      // 2M u16 each = 4 MB
  unsigned short* qws = kws + (size_t)BT * NH;
  unsigned short* vws = qws + (size_t)BT * NH;
  float* out = (float*)d_out;

  proj_kernel<<<512, 256, 0, stream>>>(x, Wk, Wq, Wv, kws, qws, vws);
  attn_kernel<<<dim3(32, 16), 256, 0, stream>>>(kws, qws, vws, out);
}

// Round 4
// 156.887 us; speedup vs baseline: 3.2171x; 1.0970x over previous
//
#include <hip/hip_runtime.h>
#include <math.h>

#define BT 32768   // B*T
#define NC 448     // n_embd
#define NH 64      // head_size
#define TT 2048    // T

typedef __bf16 bf16x8 __attribute__((ext_vector_type(8)));
typedef float  f32x4  __attribute__((ext_vector_type(4)));

// fp32 -> bf16 (RNE)
__device__ __forceinline__ unsigned short f2bf(float f) {
  unsigned u = __builtin_bit_cast(unsigned, f);
  return (unsigned short)((u + 0x7FFFu + ((u >> 16) & 1u)) >> 16);
}
__device__ __forceinline__ ushort4 f2bf4(float4 v) {
  ushort4 b; b.x = f2bf(v.x); b.y = f2bf(v.y); b.z = f2bf(v.z); b.w = f2bf(v.w);
  return b;
}

// Swizzled 64x64 bf16 tile: element (row, c) at row*64 + (((c>>3) ^ (row&7))<<3) + (c&7)
// b128 fragment reads are <=2-way bank aliased (free, m136).

// ============ projection ============
// grid (512, 3): blockIdx.x = 64-row tile, blockIdx.y = projection p (0=k,1=q,2=v).
// 64 rows x 64 cols per block; LDS double-buffered (2x8KB x + 2x8KB W), register
// prefetch of next K-chunk, ONE barrier per chunk. 5 blocks/CU (LDS-limited).
// Outputs (bf16, d_ws):
//   kws: per (b,kt) 64x64 K-rows swizzled tile image (attn copies verbatim)
//   qws: natural [R][h], pre-scaled by log2e/sqrt(448)
//   vws: per (b,kt) 64x64 V^T ([h][j]) swizzled tile image
__global__ __launch_bounds__(256) void proj_kernel(
    const float* __restrict__ x, const float* __restrict__ Wk,
    const float* __restrict__ Wq, const float* __restrict__ Wv,
    unsigned short* __restrict__ kws, unsigned short* __restrict__ qws,
    unsigned short* __restrict__ vws)
{
  __shared__ unsigned short xs[2][4096];    // [r][c] swizzled, dbuf
  __shared__ unsigned short wsm[2][4096];   // [o][c] swizzled, dbuf
  const int tid = threadIdx.x;
  const int w = tid >> 6, lane = tid & 63;
  const int q = lane >> 4, l15 = lane & 15;
  const int r0 = blockIdx.x * 64;
  const int p = blockIdx.y;
  const float* W = (p == 0) ? Wk : ((p == 1) ? Wq : Wv);

  f32x4 acc[4];
#pragma unroll
  for (int i = 0; i < 4; ++i) acc[i] = f32x4{0.f, 0.f, 0.f, 0.f};

  const int c0 = (tid & 15) * 4, r_ = tid >> 4;

  // prefetch chunk 0
  float4 xr[4], wr[4];
#pragma unroll
  for (int i = 0; i < 4; ++i) {
    xr[i] = *(const float4*)&x[(size_t)(r0 + r_ + 16 * i) * NC + c0];
    wr[i] = *(const float4*)&W[(size_t)(r_ + 16 * i) * NC + c0];
  }

  for (int ch = 0; ch < 7; ++ch) {
    const int cur = ch & 1;
    // regs -> LDS (swizzled)
#pragma unroll
    for (int i = 0; i < 4; ++i) {
      int r = r_ + 16 * i;
      int off = r * 64 + (((c0 >> 3) ^ (r & 7)) << 3) + (c0 & 7);
      *(ushort4*)&xs[cur][off]  = f2bf4(xr[i]);
      *(ushort4*)&wsm[cur][off] = f2bf4(wr[i]);
    }
    __syncthreads();
    // prefetch next chunk
    if (ch < 6) {
      int kc = (ch + 1) * 64;
#pragma unroll
      for (int i = 0; i < 4; ++i) {
        xr[i] = *(const float4*)&x[(size_t)(r0 + r_ + 16 * i) * NC + kc + c0];
        wr[i] = *(const float4*)&W[(size_t)(r_ + 16 * i) * NC + kc + c0];
      }
    }
    // compute: wave w covers x-rows w*16..+16, all 64 W-rows
#pragma unroll
    for (int ks = 0; ks < 2; ++ks) {
      int xrow = w * 16 + l15;
      int g = q + 4 * ks;
      bf16x8 xf = *(const bf16x8*)&xs[cur][xrow * 64 + ((g ^ (xrow & 7)) << 3)];
#pragma unroll
      for (int t = 0; t < 4; ++t) {
        int wrow = t * 16 + l15;
        bf16x8 wf = *(const bf16x8*)&wsm[cur][wrow * 64 + ((g ^ (wrow & 7)) << 3)];
        if (p == 0)   // k: operand-swapped -> D = k^T tile [h][j]
          acc[t] = __builtin_amdgcn_mfma_f32_16x16x32_bf16(wf, xf, acc[t], 0, 0, 0);
        else          // q, v: natural -> D[r][h]
          acc[t] = __builtin_amdgcn_mfma_f32_16x16x32_bf16(xf, wf, acc[t], 0, 0, 0);
      }
    }
  }

  const size_t tile = (size_t)blockIdx.x * 4096;
  if (p == 0) {
    // lane holds k^T[h = t*16+q*4+rr][j = w*16+l15]; swizzled ushort4 stores
#pragma unroll
    for (int t = 0; t < 4; ++t) {
      int j = w * 16 + l15;
      ushort4 bb; bb.x = f2bf(acc[t][0]); bb.y = f2bf(acc[t][1]);
      bb.z = f2bf(acc[t][2]); bb.w = f2bf(acc[t][3]);
      *(ushort4*)&kws[tile + j * 64 + (((2 * t + (q >> 1)) ^ (j & 7)) << 3) + ((q & 1) << 2)] = bb;
    }
  } else if (p == 1) {
    // q: natural [R][h], scaled by log2(e)/sqrt(448)
    const float qs = 0.068161075f;
#pragma unroll
    for (int t = 0; t < 4; ++t) {
      int h = t * 16 + l15;
#pragma unroll
      for (int rr = 0; rr < 4; ++rr) {
        int R = r0 + w * 16 + q * 4 + rr;
        qws[(size_t)R * 64 + h] = f2bf(acc[t][rr] * qs);
      }
    }
  } else {
    // v: lane holds v[j = w*16+q*4+rr][h = t*16+l15] -> V^T tile [h][j], ushort4
#pragma unroll
    for (int t = 0; t < 4; ++t) {
      int h = t * 16 + l15;
      ushort4 bb; bb.x = f2bf(acc[t][0]); bb.y = f2bf(acc[t][1]);
      bb.z = f2bf(acc[t][2]); bb.w = f2bf(acc[t][3]);
      *(ushort4*)&vws[tile + h * 64 + (((2 * w + (q >> 1)) ^ (h & 7)) << 3) + ((q & 1) << 2)] = bb;
    }
  }
}

// ============ flash attention (causal), S^T formulation ============
// grid (32,16), qt = 31-bx; 256 thr = 4 waves; wave w owns 16 q-rows (i = l15).
// S^T = K.Q^T  -> softmax state per-lane (i = l15) -> P via wave-private LDS
// round-trip -> O = P.V with V^T tiles. K/V double-buffered, register prefetch,
// ONE barrier per iteration.
__global__ __launch_bounds__(256) void attn_kernel(
    const unsigned short* __restrict__ kws, const unsigned short* __restrict__ qws,
    const unsigned short* __restrict__ vws, float* __restrict__ out)
{
  __shared__ unsigned short ksm[2][4096];
  __shared__ unsigned short vtm[2][4096];
  __shared__ unsigned short psm[4096];
  const int qt = 31 - (int)blockIdx.x, b = blockIdx.y;
  const int tid = threadIdx.x;
  const int w = tid >> 6, lane = tid & 63;
  const int q = lane >> 4, l15 = lane & 15;
  const int t0 = b * TT + qt * 64;
  const int l7 = l15 & 7;

  // Q fragments (B-operand: lane i = l15, contiguous c)
  bf16x8 qf[2];
#pragma unroll
  for (int ks = 0; ks < 2; ++ks)
    qf[ks] = *(const bf16x8*)&qws[(size_t)(t0 + w * 16 + l15) * 64 + 32 * ks + q * 8];

  f32x4 oacc[4];
#pragma unroll
  for (int ht = 0; ht < 4; ++ht) oacc[ht] = f32x4{0.f, 0.f, 0.f, 0.f};
  float m_i = -INFINITY, l_i = 0.f;   // per-lane: row i = l15

  // register prefetch of tile kt (pre-swizzled global image -> linear copy)
  uint4 kr0, kr1, vr0, vr1;
  {
    const unsigned short* kt_ = kws + (size_t)(b * 32 + 0) * 4096;
    const unsigned short* vt_ = vws + (size_t)(b * 32 + 0) * 4096;
    kr0 = *(const uint4*)&kt_[tid * 8];  kr1 = *(const uint4*)&kt_[2048 + tid * 8];
    vr0 = *(const uint4*)&vt_[tid * 8];  vr1 = *(const uint4*)&vt_[2048 + tid * 8];
  }

  for (int kt = 0; kt <= qt; ++kt) {
    const int cur = kt & 1;
    *(uint4*)&ksm[cur][tid * 8] = kr0;  *(uint4*)&ksm[cur][2048 + tid * 8] = kr1;
    *(uint4*)&vtm[cur][tid * 8] = vr0;  *(uint4*)&vtm[cur][2048 + tid * 8] = vr1;
    __syncthreads();
    if (kt < qt) {
      const unsigned short* kt_ = kws + (size_t)(b * 32 + kt + 1) * 4096;
      const unsigned short* vt_ = vws + (size_t)(b * 32 + kt + 1) * 4096;
      kr0 = *(const uint4*)&kt_[tid * 8];  kr1 = *(const uint4*)&kt_[2048 + tid * 8];
      vr0 = *(const uint4*)&vt_[tid * 8];  vr1 = *(const uint4*)&vt_[2048 + tid * 8];
    }

    // S^T = K . Q^T : D[m=j][n=i]; lane: j = jt*16+q*4+rr, i = l15
    f32x4 sacc[4];
#pragma unroll
    for (int jt = 0; jt < 4; ++jt) sacc[jt] = f32x4{0.f, 0.f, 0.f, 0.f};
#pragma unroll
    for (int jt = 0; jt < 4; ++jt) {
      int j = jt * 16 + l15;
#pragma unroll
      for (int ks = 0; ks < 2; ++ks) {
        bf16x8 kf = *(const bf16x8*)&ksm[cur][j * 64 + (((q + 4 * ks) ^ (j & 7)) << 3)];
        sacc[jt] = __builtin_amdgcn_mfma_f32_16x16x32_bf16(kf, qf[ks], sacc[jt], 0, 0, 0);
      }
    }

    if (kt == qt) {   // causal: mask j > i on the diagonal tile
      int iloc = w * 16 + l15;
#pragma unroll
      for (int jt = 0; jt < 4; ++jt)
#pragma unroll
        for (int rr = 0; rr < 4; ++rr)
          if (jt * 16 + q * 4 + rr > iloc) sacc[jt][rr] = -INFINITY;
    }

    // online softmax: all 16 values in this lane share row i = l15
    float mx = -INFINITY;
#pragma unroll
    for (int jt = 0; jt < 4; ++jt)
#pragma unroll
      for (int rr = 0; rr < 4; ++rr) mx = fmaxf(mx, sacc[jt][rr]);
    mx = fmaxf(mx, __shfl_xor(mx, 16));
    mx = fmaxf(mx, __shfl_xor(mx, 32));
    float mn = fmaxf(m_i, mx);
    float alpha = exp2f(m_i - mn);
    m_i = mn;
    float p[4][4], rs = 0.f;
#pragma unroll
    for (int jt = 0; jt < 4; ++jt)
#pragma unroll
      for (int rr = 0; rr < 4; ++rr) {
        float pv = exp2f(sacc[jt][rr] - mn);
        p[jt][rr] = pv; rs += pv;
      }
    rs += __shfl_xor(rs, 16);
    rs += __shfl_xor(rs, 32);
    l_i = l_i * alpha + rs;

    // alpha transpose: O rows are i = q*4+rr; alpha lives at lane l15 = i
    float a_t[4];
#pragma unroll
    for (int rr = 0; rr < 4; ++rr) a_t[rr] = __shfl(alpha, q * 4 + rr);
#pragma unroll
    for (int ht = 0; ht < 4; ++ht)
#pragma unroll
      for (int rr = 0; rr < 4; ++rr) oacc[ht][rr] *= a_t[rr];

    // P -> LDS (wave-private rows, no barrier): row = w*16+l15, cols j = jt*16+q*4+rr
    {
      int row = w * 16 + l15;
#pragma unroll
      for (int jt = 0; jt < 4; ++jt) {
        ushort4 bb; bb.x = f2bf(p[jt][0]); bb.y = f2bf(p[jt][1]);
        bb.z = f2bf(p[jt][2]); bb.w = f2bf(p[jt][3]);
        *(ushort4*)&psm[row * 64 + (((2 * jt + (q >> 1)) ^ l7) << 3) + ((q & 1) << 2)] = bb;
      }
    }

    // O += P . V : A = P rows (m=i=l15), B = V^T rows (n=h=l15 per ht)
#pragma unroll
    for (int ks2 = 0; ks2 < 2; ++ks2) {
      int prow = w * 16 + l15;
      bf16x8 pf = *(const bf16x8*)&psm[prow * 64 + (((q + 4 * ks2) ^ l7) << 3)];
#pragma unroll
      for (int ht = 0; ht < 4; ++ht) {
        int h = ht * 16 + l15;
        bf16x8 vf = *(const bf16x8*)&vtm[cur][h * 64 + (((q + 4 * ks2) ^ l7) << 3)];
        oacc[ht] = __builtin_amdgcn_mfma_f32_16x16x32_bf16(pf, vf, oacc[ht], 0, 0, 0);
      }
    }
  }

  // epilogue: O[m=i=q*4+rr][n=h]; l lives at lane l15 = i -> transpose via shuffle
  float l_t[4];
#pragma unroll
  for (int rr = 0; rr < 4; ++rr) l_t[rr] = __shfl(l_i, q * 4 + rr);
#pragma unroll
  for (int rr = 0; rr < 4; ++rr) {
    float inv = 1.f / l_t[rr];
    int R = t0 + w * 16 + q * 4 + rr;
#pragma unroll
    for (int ht = 0; ht < 4; ++ht)
      out[(size_t)R * 64 + ht * 16 + l15] = oacc[ht][rr] * inv;
  }
}

extern "C" void kernel_launch(void* const* d_in, const int* in_sizes, int n_in,
                              void* d_out, int out_size, void* d_ws, size_t ws_size,
                              hipStream_t stream) {
  const float* x  = (const float*)d_in[0];
  const float* Wk = (const float*)d_in[1];
  const float* Wq = (const float*)d_in[2];
  const float* Wv = (const float*)d_in[3];
  unsigned short* kws = (unsigned short*)d_ws;      // 2M u16 each = 4 MB
  unsigned short* qws = kws + (size_t)BT * NH;
  unsigned short* vws = qws + (size_t)BT * NH;
  float* out = (float*)d_out;

  proj_kernel<<<dim3(512, 3), 256, 0, stream>>>(x, Wk, Wq, Wv, kws, qws, vws);
  attn_kernel<<<dim3(32, 16), 256, 0, stream>>>(kws, qws, vws, out);
}

// Round 5
// 147.118 us; speedup vs baseline: 3.4307x; 1.0664x over previous
//
#include <hip/hip_runtime.h>
#include <math.h>

#define BT 32768   // B*T
#define NC 448     // n_embd
#define NH 64      // head_size
#define TT 2048    // T

typedef __bf16 bf16x8 __attribute__((ext_vector_type(8)));
typedef float  f32x4  __attribute__((ext_vector_type(4)));

// fp32 -> bf16 (RNE)
__device__ __forceinline__ unsigned short f2bf(float f) {
  unsigned u = __builtin_bit_cast(unsigned, f);
  return (unsigned short)((u + 0x7FFFu + ((u >> 16) & 1u)) >> 16);
}
__device__ __forceinline__ ushort4 f2bf4(float4 v) {
  ushort4 b; b.x = f2bf(v.x); b.y = f2bf(v.y); b.z = f2bf(v.z); b.w = f2bf(v.w);
  return b;
}

// Swizzled 64x64 bf16 tile: element (row, c) at row*64 + (((c>>3) ^ (row&7))<<3) + (c&7)

// ============ projection ============ (unchanged from round 4)
__global__ __launch_bounds__(256) void proj_kernel(
    const float* __restrict__ x, const float* __restrict__ Wk,
    const float* __restrict__ Wq, const float* __restrict__ Wv,
    unsigned short* __restrict__ kws, unsigned short* __restrict__ qws,
    unsigned short* __restrict__ vws)
{
  __shared__ unsigned short xs[2][4096];
  __shared__ unsigned short wsm[2][4096];
  const int tid = threadIdx.x;
  const int w = tid >> 6, lane = tid & 63;
  const int q = lane >> 4, l15 = lane & 15;
  const int r0 = blockIdx.x * 64;
  const int p = blockIdx.y;
  const float* W = (p == 0) ? Wk : ((p == 1) ? Wq : Wv);

  f32x4 acc[4];
#pragma unroll
  for (int i = 0; i < 4; ++i) acc[i] = f32x4{0.f, 0.f, 0.f, 0.f};

  const int c0 = (tid & 15) * 4, r_ = tid >> 4;

  float4 xr[4], wr[4];
#pragma unroll
  for (int i = 0; i < 4; ++i) {
    xr[i] = *(const float4*)&x[(size_t)(r0 + r_ + 16 * i) * NC + c0];
    wr[i] = *(const float4*)&W[(size_t)(r_ + 16 * i) * NC + c0];
  }

  for (int ch = 0; ch < 7; ++ch) {
    const int cur = ch & 1;
#pragma unroll
    for (int i = 0; i < 4; ++i) {
      int r = r_ + 16 * i;
      int off = r * 64 + (((c0 >> 3) ^ (r & 7)) << 3) + (c0 & 7);
      *(ushort4*)&xs[cur][off]  = f2bf4(xr[i]);
      *(ushort4*)&wsm[cur][off] = f2bf4(wr[i]);
    }
    __syncthreads();
    if (ch < 6) {
      int kc = (ch + 1) * 64;
#pragma unroll
      for (int i = 0; i < 4; ++i) {
        xr[i] = *(const float4*)&x[(size_t)(r0 + r_ + 16 * i) * NC + kc + c0];
        wr[i] = *(const float4*)&W[(size_t)(r_ + 16 * i) * NC + kc + c0];
      }
    }
#pragma unroll
    for (int ks = 0; ks < 2; ++ks) {
      int xrow = w * 16 + l15;
      int g = q + 4 * ks;
      bf16x8 xf = *(const bf16x8*)&xs[cur][xrow * 64 + ((g ^ (xrow & 7)) << 3)];
#pragma unroll
      for (int t = 0; t < 4; ++t) {
        int wrow = t * 16 + l15;
        bf16x8 wf = *(const bf16x8*)&wsm[cur][wrow * 64 + ((g ^ (wrow & 7)) << 3)];
        if (p == 0)
          acc[t] = __builtin_amdgcn_mfma_f32_16x16x32_bf16(wf, xf, acc[t], 0, 0, 0);
        else
          acc[t] = __builtin_amdgcn_mfma_f32_16x16x32_bf16(xf, wf, acc[t], 0, 0, 0);
      }
    }
  }

  const size_t tile = (size_t)blockIdx.x * 4096;
  if (p == 0) {
#pragma unroll
    for (int t = 0; t < 4; ++t) {
      int j = w * 16 + l15;
      ushort4 bb; bb.x = f2bf(acc[t][0]); bb.y = f2bf(acc[t][1]);
      bb.z = f2bf(acc[t][2]); bb.w = f2bf(acc[t][3]);
      *(ushort4*)&kws[tile + j * 64 + (((2 * t + (q >> 1)) ^ (j & 7)) << 3) + ((q & 1) << 2)] = bb;
    }
  } else if (p == 1) {
    const float qs = 0.068161075f;   // log2(e)/sqrt(448)
#pragma unroll
    for (int t = 0; t < 4; ++t) {
      int h = t * 16 + l15;
#pragma unroll
      for (int rr = 0; rr < 4; ++rr) {
        int R = r0 + w * 16 + q * 4 + rr;
        qws[(size_t)R * 64 + h] = f2bf(acc[t][rr] * qs);
      }
    }
  } else {
#pragma unroll
    for (int t = 0; t < 4; ++t) {
      int h = t * 16 + l15;
      ushort4 bb; bb.x = f2bf(acc[t][0]); bb.y = f2bf(acc[t][1]);
      bb.z = f2bf(acc[t][2]); bb.w = f2bf(acc[t][3]);
      *(ushort4*)&vws[tile + h * 64 + (((2 * w + (q >> 1)) ^ (h & 7)) << 3) + ((q & 1) << 2)] = bb;
    }
  }
}

// ============ flash attention, split-K (flash-decoding) ============
// grid (48,16). bx mapping (roughly longest-first):
//   bx<16 : qt=16+bx, kt [0,16), partial slot 0 (no diagonal)
//   16-31 : qt=47-bx, kt [16,qt+1), partial slot 1 (has diagonal)
//   32-47 : qt=47-bx, kt [0,qt+1), single chunk -> writes out directly
// Partials store unnormalized O (fp32) + per-row m,l; combine_kernel merges.
__global__ __launch_bounds__(256) void attn_partial(
    const unsigned short* __restrict__ kws, const unsigned short* __restrict__ qws,
    const unsigned short* __restrict__ vws, float* __restrict__ out,
    float* __restrict__ opart, float* __restrict__ mlpart)
{
  __shared__ unsigned short ksm[2][4096];
  __shared__ unsigned short vtm[2][4096];
  __shared__ unsigned short psm[4096];
  const int bx = blockIdx.x, b = blockIdx.y;
  int qt, kt0, ktn, ci; bool direct;
  if (bx < 16)      { qt = 16 + bx; kt0 = 0;  ktn = 16;     ci = 0; direct = false; }
  else if (bx < 32) { qt = 47 - bx; kt0 = 16; ktn = qt + 1; ci = 1; direct = false; }
  else              { qt = 47 - bx; kt0 = 0;  ktn = qt + 1; ci = 0; direct = true;  }
  const int nt = ktn - kt0;

  const int tid = threadIdx.x;
  const int w = tid >> 6, lane = tid & 63;
  const int q = lane >> 4, l15 = lane & 15;
  const int t0 = b * TT + qt * 64;
  const int l7 = l15 & 7;

  bf16x8 qf[2];
#pragma unroll
  for (int ks = 0; ks < 2; ++ks)
    qf[ks] = *(const bf16x8*)&qws[(size_t)(t0 + w * 16 + l15) * 64 + 32 * ks + q * 8];

  f32x4 oacc[4];
#pragma unroll
  for (int ht = 0; ht < 4; ++ht) oacc[ht] = f32x4{0.f, 0.f, 0.f, 0.f};
  float m_i = -INFINITY, l_i = 0.f;   // per-lane, row i = w*16 + l15

  uint4 kr0, kr1, vr0, vr1;
  {
    const unsigned short* kt_ = kws + (size_t)(b * 32 + kt0) * 4096;
    const unsigned short* vt_ = vws + (size_t)(b * 32 + kt0) * 4096;
    kr0 = *(const uint4*)&kt_[tid * 8];  kr1 = *(const uint4*)&kt_[2048 + tid * 8];
    vr0 = *(const uint4*)&vt_[tid * 8];  vr1 = *(const uint4*)&vt_[2048 + tid * 8];
  }

  for (int it = 0; it < nt; ++it) {
    const int kt = kt0 + it;
    const int cur = it & 1;
    *(uint4*)&ksm[cur][tid * 8] = kr0;  *(uint4*)&ksm[cur][2048 + tid * 8] = kr1;
    *(uint4*)&vtm[cur][tid * 8] = vr0;  *(uint4*)&vtm[cur][2048 + tid * 8] = vr1;
    __syncthreads();
    if (it + 1 < nt) {
      const unsigned short* kt_ = kws + (size_t)(b * 32 + kt + 1) * 4096;
      const unsigned short* vt_ = vws + (size_t)(b * 32 + kt + 1) * 4096;
      kr0 = *(const uint4*)&kt_[tid * 8];  kr1 = *(const uint4*)&kt_[2048 + tid * 8];
      vr0 = *(const uint4*)&vt_[tid * 8];  vr1 = *(const uint4*)&vt_[2048 + tid * 8];
    }

    // S^T = K . Q^T : lane j = jt*16+q*4+rr, i = l15
    f32x4 sacc[4];
#pragma unroll
    for (int jt = 0; jt < 4; ++jt) sacc[jt] = f32x4{0.f, 0.f, 0.f, 0.f};
#pragma unroll
    for (int jt = 0; jt < 4; ++jt) {
      int j = jt * 16 + l15;
#pragma unroll
      for (int ks = 0; ks < 2; ++ks) {
        bf16x8 kf = *(const bf16x8*)&ksm[cur][j * 64 + (((q + 4 * ks) ^ (j & 7)) << 3)];
        sacc[jt] = __builtin_amdgcn_mfma_f32_16x16x32_bf16(kf, qf[ks], sacc[jt], 0, 0, 0);
      }
    }

    if (kt == qt) {   // diagonal tile: mask j > i
      int iloc = w * 16 + l15;
#pragma unroll
      for (int jt = 0; jt < 4; ++jt)
#pragma unroll
        for (int rr = 0; rr < 4; ++rr)
          if (jt * 16 + q * 4 + rr > iloc) sacc[jt][rr] = -INFINITY;
    }

    // online softmax (per-lane row state)
    float mx = -INFINITY;
#pragma unroll
    for (int jt = 0; jt < 4; ++jt)
#pragma unroll
      for (int rr = 0; rr < 4; ++rr) mx = fmaxf(mx, sacc[jt][rr]);
    mx = fmaxf(mx, __shfl_xor(mx, 16));
    mx = fmaxf(mx, __shfl_xor(mx, 32));
    float mn = fmaxf(m_i, mx);
    float alpha = exp2f(m_i - mn);
    m_i = mn;
    float p[4][4], rs = 0.f;
#pragma unroll
    for (int jt = 0; jt < 4; ++jt)
#pragma unroll
      for (int rr = 0; rr < 4; ++rr) {
        float pv = exp2f(sacc[jt][rr] - mn);
        p[jt][rr] = pv; rs += pv;
      }
    rs += __shfl_xor(rs, 16);
    rs += __shfl_xor(rs, 32);
    l_i = l_i * alpha + rs;

    float a_t[4];
#pragma unroll
    for (int rr = 0; rr < 4; ++rr) a_t[rr] = __shfl(alpha, q * 4 + rr);
#pragma unroll
    for (int ht = 0; ht < 4; ++ht)
#pragma unroll
      for (int rr = 0; rr < 4; ++rr) oacc[ht][rr] *= a_t[rr];

    // P -> LDS (wave-private rows)
    {
      int row = w * 16 + l15;
#pragma unroll
      for (int jt = 0; jt < 4; ++jt) {
        ushort4 bb; bb.x = f2bf(p[jt][0]); bb.y = f2bf(p[jt][1]);
        bb.z = f2bf(p[jt][2]); bb.w = f2bf(p[jt][3]);
        *(ushort4*)&psm[row * 64 + (((2 * jt + (q >> 1)) ^ l7) << 3) + ((q & 1) << 2)] = bb;
      }
    }

    // O += P . V
#pragma unroll
    for (int ks2 = 0; ks2 < 2; ++ks2) {
      int prow = w * 16 + l15;
      bf16x8 pf = *(const bf16x8*)&psm[prow * 64 + (((q + 4 * ks2) ^ l7) << 3)];
#pragma unroll
      for (int ht = 0; ht < 4; ++ht) {
        int h = ht * 16 + l15;
        bf16x8 vf = *(const bf16x8*)&vtm[cur][h * 64 + (((q + 4 * ks2) ^ l7) << 3)];
        oacc[ht] = __builtin_amdgcn_mfma_f32_16x16x32_bf16(pf, vf, oacc[ht], 0, 0, 0);
      }
    }
  }

  if (direct) {
    float l_t[4];
#pragma unroll
    for (int rr = 0; rr < 4; ++rr) l_t[rr] = __shfl(l_i, q * 4 + rr);
#pragma unroll
    for (int rr = 0; rr < 4; ++rr) {
      float inv = 1.f / l_t[rr];
      int R = t0 + w * 16 + q * 4 + rr;
#pragma unroll
      for (int ht = 0; ht < 4; ++ht)
        out[(size_t)R * 64 + ht * 16 + l15] = oacc[ht][rr] * inv;
    }
  } else {
    const size_t slot = (size_t)(b * 16 + (qt - 16)) * 2 + ci;
    float* Op = opart + slot * 4096;
#pragma unroll
    for (int rr = 0; rr < 4; ++rr) {
      int rloc = w * 16 + q * 4 + rr;
#pragma unroll
      for (int ht = 0; ht < 4; ++ht)
        Op[rloc * 64 + ht * 16 + l15] = oacc[ht][rr];
    }
    if (q == 0) {
      mlpart[slot * 128 + w * 16 + l15]      = m_i;
      mlpart[slot * 128 + 64 + w * 16 + l15] = l_i;
    }
  }
}

// ============ combine: merge the two partials for qt in [16,32) ============
__global__ __launch_bounds__(256) void combine_kernel(
    const float* __restrict__ opart, const float* __restrict__ mlpart,
    float* __restrict__ out)
{
  const int qtc = blockIdx.x, b = blockIdx.y;
  const int qt = 16 + qtc;
  const int t = threadIdx.x;
  const int r = t >> 2, c0 = (t & 3) * 16;
  const size_t s0 = (size_t)(b * 16 + qtc) * 2;

  float m0 = mlpart[s0 * 128 + r],       l0 = mlpart[s0 * 128 + 64 + r];
  float m1 = mlpart[(s0 + 1) * 128 + r], l1 = mlpart[(s0 + 1) * 128 + 64 + r];
  float m  = fmaxf(m0, m1);
  float w0 = exp2f(m0 - m), w1 = exp2f(m1 - m);
  float inv = 1.f / (w0 * l0 + w1 * l1);
  w0 *= inv; w1 *= inv;

  const float* O0 = opart + s0 * 4096 + r * 64;
  const float* O1 = opart + (s0 + 1) * 4096 + r * 64;
  float* op = out + (size_t)(b * TT + qt * 64 + r) * 64;
#pragma unroll
  for (int j = 0; j < 4; ++j) {
    float4 a  = *(const float4*)&O0[c0 + j * 4];
    float4 bb = *(const float4*)&O1[c0 + j * 4];
    float4 o;
    o.x = w0 * a.x + w1 * bb.x;  o.y = w0 * a.y + w1 * bb.y;
    o.z = w0 * a.z + w1 * bb.z;  o.w = w0 * a.w + w1 * bb.w;
    *(float4*)&op[c0 + j * 4] = o;
  }
}

extern "C" void kernel_launch(void* const* d_in, const int* in_sizes, int n_in,
                              void* d_out, int out_size, void* d_ws, size_t ws_size,
                              hipStream_t stream) {
  const float* x  = (const float*)d_in[0];
  const float* Wk = (const float*)d_in[1];
  const float* Wq = (const float*)d_in[2];
  const float* Wv = (const float*)d_in[3];
  unsigned short* kws = (unsigned short*)d_ws;          // 4 MB
  unsigned short* qws = kws + (size_t)BT * NH;          // 4 MB
  unsigned short* vws = qws + (size_t)BT * NH;          // 4 MB
  float* opart  = (float*)(vws + (size_t)BT * NH);      // 512 slots * 16 KB = 8 MB
  float* mlpart = opart + (size_t)512 * 4096;           // 256 KB  (total ~20.9 MB)
  float* out = (float*)d_out;

  proj_kernel<<<dim3(512, 3), 256, 0, stream>>>(x, Wk, Wq, Wv, kws, qws, vws);
  attn_partial<<<dim3(48, 16), 256, 0, stream>>>(kws, qws, vws, out, opart, mlpart);
  combine_kernel<<<dim3(16, 16), 256, 0, stream>>>(opart, mlpart, out);
}